// Round 18
// baseline (1044.884 us; speedup 1.0000x reference)
//
#include <hip/hip_runtime.h>
#include <hip/hip_bf16.h>
#include <cstddef>
#include <cstdint>

// ---------------------------------------------------------------- types
typedef __bf16 bf16_t;
typedef __fp16 fp16_t;
typedef __attribute__((ext_vector_type(2))) __fp16 h16x2;   // builtin-native f16 pair
typedef __attribute__((ext_vector_type(8))) __bf16 bf16x8;
typedef __attribute__((ext_vector_type(4))) float f32x4;
typedef __attribute__((ext_vector_type(2))) unsigned u32x2;

#define B_  64
#define T_  2048
#define E_  512
#define H_  32
#define G_  96          // 3*H
#define N2_ 192         // both directions
#define OUT_ 131

//  r,z: scaled by C1 = -log2(e)  -> sigmoid(a) = rcp(1+exp2(C1*a))
//  n:   scaled by C2 = 2*log2(e) -> tanh(y)    = 1-2*rcp(1+exp2(C2*y))
#define C1_ (-1.44269504088896340736f)
#define C2_ ( 2.88539008177792681472f)

// single-instruction DPP rotate within 16-lane rows (no tied old-copy)
#define MOVDPP(out_, in_, N_)                                               \
    asm("v_mov_b32_dpp %0, %1 row_ror:" #N_ " row_mask:0xf bank_mask:0xf"   \
        : "=v"(out_) : "v"(in_))

// ---------------------------------------------------------------- prep: W_ih->bf16, bias, zero flags
__global__ void prep_kernel(const float* __restrict__ Wf, const float* __restrict__ Wb,
                            const float* __restrict__ bf_, const float* __restrict__ bb_,
                            const float* __restrict__ bhf, const float* __restrict__ bhb,
                            bf16_t* __restrict__ Wbf, float* __restrict__ bias,
                            int* __restrict__ done) {
    int idx = blockIdx.x * 256 + threadIdx.x;        // 0 .. 98303
    int g = idx >> 9, k = idx & 511;
    float v = (g < G_) ? Wf[g * E_ + k] : Wb[(g - G_) * E_ + k];
    Wbf[idx] = (bf16_t)v;
    if (idx < N2_) {
        int dn = (idx >= G_) ? 1 : 0;
        int lg = idx - G_ * dn;
        const float* bi = dn ? bb_ : bf_;
        const float* bh = dn ? bhb : bhf;
        bias[idx] = bi[lg] + ((lg < 64) ? bh[lg] : 0.0f);   // fold b_hh for r,z only
    }
    if (idx < B_) done[idx] = 0;
}

// ---------------------------------------------------------------- fused proj + rec
// Blocks 0..63: rec role (batch = blockIdx.x); spin on done[batch]==64.
// Blocks 64..4159: proj role; bx = blockIdx.x-64; n-idx = bx&1 (innermost for
// L2 x-reuse), m-idx = bx>>1. Each proj block signals done[batch] when stored.
__global__ __launch_bounds__(256) void fused_kernel(
    const float* x,            // [131072][512] f32
    const bf16_t* Wbf,         // [192][512] bf16
    const float* bias,         // [192]
    const int* src_len,        // [64]
    const float* Whh_f, const float* bhh_f,
    const float* Whh_b, const float* bhh_b,
    float* xp4,                // packed, prescaled, bwd-reversed
    float* hout,               // [B][64]
    int* done)                 // [64]
{
    __shared__ bf16_t Alds[64][72];
    __shared__ bf16_t Blds[96][72];

    if (blockIdx.x >= 64) {
        // ======================= proj role =======================
        const int bx   = blockIdx.x - 64;
        const int tid  = threadIdx.x;
        const int lane = tid & 63;
        const int w    = tid >> 6;
        const int wm   = w & 1;
        const int wn   = w >> 1;
        const int m0   = (bx >> 1) * 64;
        const int n0   = (bx & 1) * 96;

        const int arow = tid >> 2;
        const int acol = (tid & 3) * 16;

        f32x4 acc[2][3];
        #pragma unroll
        for (int i = 0; i < 2; ++i)
            #pragma unroll
            for (int jn = 0; jn < 3; ++jn)
                acc[i][jn] = (f32x4){0.f, 0.f, 0.f, 0.f};

        for (int kt = 0; kt < 8; ++kt) {
            const int c0 = kt * 64;
            __syncthreads();
            {
                const float* asrc = x + (size_t)(m0 + arow) * E_ + c0 + acol;
                float4 v0 = *(const float4*)(asrc + 0);
                float4 v1 = *(const float4*)(asrc + 4);
                float4 v2 = *(const float4*)(asrc + 8);
                float4 v3 = *(const float4*)(asrc + 12);
                bf16x8 pa, pb;
                pa[0]=(bf16_t)v0.x; pa[1]=(bf16_t)v0.y; pa[2]=(bf16_t)v0.z; pa[3]=(bf16_t)v0.w;
                pa[4]=(bf16_t)v1.x; pa[5]=(bf16_t)v1.y; pa[6]=(bf16_t)v1.z; pa[7]=(bf16_t)v1.w;
                pb[0]=(bf16_t)v2.x; pb[1]=(bf16_t)v2.y; pb[2]=(bf16_t)v2.z; pb[3]=(bf16_t)v2.w;
                pb[4]=(bf16_t)v3.x; pb[5]=(bf16_t)v3.y; pb[6]=(bf16_t)v3.z; pb[7]=(bf16_t)v3.w;
                *(bf16x8*)&Alds[arow][acol]     = pa;
                *(bf16x8*)&Alds[arow][acol + 8] = pb;
            }
            #pragma unroll
            for (int i = 0; i < 3; ++i) {
                int u = tid + i * 256;
                int brow = u >> 3, koff = (u & 7) * 8;
                bf16x8 bv = *(const bf16x8*)(Wbf + (size_t)(n0 + brow) * E_ + c0 + koff);
                *(bf16x8*)&Blds[brow][koff] = bv;
            }
            __syncthreads();
            #pragma unroll
            for (int ks = 0; ks < 2; ++ks) {
                bf16x8 af[2], bfr[3];
                #pragma unroll
                for (int i = 0; i < 2; ++i)
                    af[i] = *(const bf16x8*)&Alds[wm * 32 + i * 16 + (lane & 15)][ks * 32 + (lane >> 4) * 8];
                #pragma unroll
                for (int jn = 0; jn < 3; ++jn)
                    bfr[jn] = *(const bf16x8*)&Blds[wn * 48 + jn * 16 + (lane & 15)][ks * 32 + (lane >> 4) * 8];
                #pragma unroll
                for (int i = 0; i < 2; ++i)
                    #pragma unroll
                    for (int jn = 0; jn < 3; ++jn)
                        acc[i][jn] = __builtin_amdgcn_mfma_f32_16x16x32_bf16(af[i], bfr[jn], acc[i][jn], 0, 0, 0);
            }
        }
        // ---- epilogue
        const int bb = m0 >> 11;
        int len = src_len[bb];
        if (len < 1) len = 1;
        if (len > T_) len = T_;
        float* xb4 = xp4 + (size_t)bb * 512 * N2_ * 4;
        #pragma unroll
        for (int i = 0; i < 2; ++i)
            #pragma unroll
            for (int jn = 0; jn < 3; ++jn) {
                int mg = m0 + wm * 32 + i * 16 + ((lane >> 4) & 3) * 4;
                int ng = n0 + wn * 48 + jn * 16 + (lane & 15);
                int lg = (ng >= G_) ? ng - G_ : ng;
                float scl = (lg < 64) ? C1_ : C2_;
                float bv  = bias[ng];
                int t = mg & (T_ - 1);
                if (ng < G_) {
                    f32x4 v;
                    #pragma unroll
                    for (int r = 0; r < 4; ++r) v[r] = scl * (acc[i][jn][r] + bv);
                    *(f32x4*)(xb4 + ((size_t)(t >> 2) * N2_ + ng) * 4) = v;
                } else {
                    #pragma unroll
                    for (int r = 0; r < 4; ++r) {
                        int trow = len - 1 - (t + r);
                        if (trow < 0) trow += T_;
                        xb4[((size_t)(trow >> 2) * N2_ + ng) * 4 + (trow & 3)] =
                            scl * (acc[i][jn][r] + bv);
                    }
                }
            }
        // ---- release: all stores visible, then count up
        __threadfence();
        __syncthreads();
        if (tid == 0) atomicAdd(&done[bb], 1);
        return;
    }

    // ======================= rec role =======================
    const int b = blockIdx.x;
    const int l = threadIdx.x;
    if (l >= 64) return;                 // 1 wave does the chain

    // acquire: wait for this batch's 64 proj blocks
    if (l == 0) {
        while (atomicAdd(&done[b], 0) < 64) {}
    }
    __threadfence();                     // wave re-converges; invalidate caches

    const int m    = l & 15;
    const int r16  = (l >> 4) & 1;
    const int dir  = l >> 5;
    const int j    = l & 31;

    const float* Whh = dir ? Whh_b : Whh_f;
    const float* bhh = dir ? bhh_b : bhh_f;

    int s_dir;
    {
        int q1;
        MOVDPP(q1, m, 1);
        s_dir = (__builtin_amdgcn_readfirstlane(q1) == 1) ? 1 : -1;
    }

    h16x2 wr[16], wz[16], wn[16];
    #pragma unroll
    for (int i = 0; i < 16; ++i) {
        int c  = (m + s_dir * i) & 15;
        int ka = c + 16 * r16;
        int kb = c + 16 * (1 - r16);
        wr[i] = (h16x2){(fp16_t)(C1_ * Whh[(j)      * H_ + ka]), (fp16_t)(C1_ * Whh[(j)      * H_ + kb])};
        wz[i] = (h16x2){(fp16_t)(C1_ * Whh[(32 + j) * H_ + ka]), (fp16_t)(C1_ * Whh[(32 + j) * H_ + kb])};
        wn[i] = (h16x2){(fp16_t)(C2_ * Whh[(64 + j) * H_ + ka]), (fp16_t)(C2_ * Whh[(64 + j) * H_ + kb])};
    }
    const float bn = C2_ * bhh[64 + j];

#if __has_builtin(__builtin_amdgcn_permlane16_swap)
    bool useX;
    {
        u32x2 pr = __builtin_amdgcn_permlane16_swap((unsigned)l, (unsigned)l, false, false);
        useX = (pr.x == (unsigned)(l ^ 16));
    }
#endif

    int len = src_len[b];
    if (len < 1) len = 1;
    if (len > T_) len = T_;
    len = __builtin_amdgcn_readfirstlane(len);

    const int off = dir * G_ + j;
    const float* xb4 = xp4 + (size_t)b * 512 * N2_ * 4;

    float hval = 0.0f;

    auto LB = [&](int q4, f32x4& vr, f32x4& vz, f32x4& vn) {
        int qq = (q4 < 512) ? q4 : 511;
        const f32x4* p = (const f32x4*)(xb4 + ((size_t)qq * N2_ + off) * 4);
        vr = p[0]; vz = p[32]; vn = p[64];
    };

    auto step = [&](float xr, float xz, float xn) {
        float hB;
#if __has_builtin(__builtin_amdgcn_permlane16_swap)
        {
            u32x2 sw = __builtin_amdgcn_permlane16_swap(
                __float_as_uint(hval), __float_as_uint(hval), false, false);
            hB = __uint_as_float(useX ? sw.x : sw.y);
        }
#else
        hB = __int_as_float(__builtin_amdgcn_ds_bpermute((l ^ 16) << 2, __float_as_int(hval)));
#endif
        auto q0 = __builtin_amdgcn_cvt_pkrtz(hval, hB);
        int qb = __builtin_bit_cast(int, q0);
        float ar = xr, az = xz, an = bn;
        {
            h16x2 p0 = __builtin_bit_cast(h16x2, qb);
            ar = __builtin_amdgcn_fdot2(p0, wr[0], ar, false);
            az = __builtin_amdgcn_fdot2(p0, wz[0], az, false);
            an = __builtin_amdgcn_fdot2(p0, wn[0], an, false);
        }
#define DOTI(N_)                                                    \
        {   int rb_;                                                \
            MOVDPP(rb_, qb, N_);                                    \
            h16x2 p_ = __builtin_bit_cast(h16x2, rb_);              \
            ar = __builtin_amdgcn_fdot2(p_, wr[N_], ar, false);     \
            az = __builtin_amdgcn_fdot2(p_, wz[N_], az, false);     \
            an = __builtin_amdgcn_fdot2(p_, wn[N_], an, false);     }
        DOTI(1)  DOTI(2)  DOTI(3)  DOTI(4)  DOTI(5)
        DOTI(6)  DOTI(7)  DOTI(8)  DOTI(9)  DOTI(10)
        DOTI(11) DOTI(12) DOTI(13) DOTI(14) DOTI(15)
#undef DOTI
        float er = __builtin_amdgcn_exp2f(ar);
        float rg = __builtin_amdgcn_rcpf(1.0f + er);
        float ez = __builtin_amdgcn_exp2f(az);
        float zg = __builtin_amdgcn_rcpf(1.0f + ez);
        float na = __builtin_fmaf(rg, an, xn);
        float eu = __builtin_amdgcn_exp2f(na);
        float u  = __builtin_amdgcn_rcpf(1.0f + eu);
        float m2 = -(ez + ez);
        float hp = hval + ez;
        hval = zg * __builtin_fmaf(m2, u, hp);
    };

    f32x4 Ar, Az, An, Cr, Cz, Cn;
    LB(0, Ar, Az, An);
    LB(1, Cr, Cz, Cn);
    int s = 0;
    while (s + 8 <= len) {
        step(Ar[0], Az[0], An[0]);
        step(Ar[1], Az[1], An[1]);
        step(Ar[2], Az[2], An[2]);
        step(Ar[3], Az[3], An[3]);
        LB((s >> 2) + 2, Ar, Az, An);
        step(Cr[0], Cz[0], Cn[0]);
        step(Cr[1], Cz[1], Cn[1]);
        step(Cr[2], Cz[2], Cn[2]);
        step(Cr[3], Cz[3], Cn[3]);
        LB((s >> 2) + 3, Cr, Cz, Cn);
        s += 8;
    }
    #pragma unroll
    for (int d = 0; d < 4; ++d)
        if (s + d < len) step(Ar[d], Az[d], An[d]);
    #pragma unroll
    for (int d = 0; d < 4; ++d)
        if (s + 4 + d < len) step(Cr[d], Cz[d], Cn[d]);

    hout[b * 64 + dir * 32 + j] = hval;
}

// ---------------------------------------------------------------- final fc
__global__ __launch_bounds__(192) void fc_kernel(
    const float* __restrict__ hbuf,     // [64][64]
    const float* __restrict__ fcW,      // [131][64]
    const float* __restrict__ fcb,      // [131]
    float* __restrict__ out)            // [64][131]
{
    __shared__ float hrow[64];
    const int b = blockIdx.x, tid = threadIdx.x;
    if (tid < 64) hrow[tid] = hbuf[b * 64 + tid];
    __syncthreads();
    if (tid < OUT_) {
        float acc = fcb[tid];
        #pragma unroll
        for (int i = 0; i < 64; ++i)
            acc = __builtin_fmaf(hrow[i], fcW[tid * 64 + i], acc);
        out[b * OUT_ + tid] = acc;
    }
}

// ---------------------------------------------------------------- launch
extern "C" void kernel_launch(void* const* d_in, const int* in_sizes, int n_in,
                              void* d_out, int out_size, void* d_ws, size_t ws_size,
                              hipStream_t stream) {
    const float* x    = (const float*)d_in[0];
    const int*   srcl = (const int*)  d_in[1];
    const float* Wihf = (const float*)d_in[3];
    const float* Whhf = (const float*)d_in[4];
    const float* bihf = (const float*)d_in[5];
    const float* bhhf = (const float*)d_in[6];
    const float* Wihb = (const float*)d_in[7];
    const float* Whhb = (const float*)d_in[8];
    const float* bihb = (const float*)d_in[9];
    const float* bhhb = (const float*)d_in[10];
    const float* fcW  = (const float*)d_in[11];
    const float* fcb  = (const float*)d_in[12];
    float* out = (float*)d_out;

    const size_t XP_BYTES   = (size_t)B_ * T_ * N2_ * 4;   // 100,663,296
    const size_t HBUF_BYTES = (size_t)B_ * 64 * 4;
    const size_t BIAS_BYTES = 1024;
    const size_t WBF_BYTES  = (size_t)N2_ * E_ * 2;
    const size_t DONE_BYTES = 256;
    if (ws_size < XP_BYTES + HBUF_BYTES + BIAS_BYTES + WBF_BYTES + DONE_BYTES) return;

    char* ws = (char*)d_ws;
    float*  xp4  = (float*)ws;
    float*  hbuf = (float*)(ws + XP_BYTES);
    float*  bias = (float*)(ws + XP_BYTES + HBUF_BYTES);
    bf16_t* Wbf  = (bf16_t*)(ws + XP_BYTES + HBUF_BYTES + BIAS_BYTES);
    int*    done = (int*)(ws + XP_BYTES + HBUF_BYTES + BIAS_BYTES + WBF_BYTES);

    prep_kernel<<<384, 256, 0, stream>>>(Wihf, Wihb, bihf, bihb, bhhf, bhhb, Wbf, bias, done);
    fused_kernel<<<64 + (B_ * T_) / 64 * 2, 256, 0, stream>>>(
        x, Wbf, bias, srcl, Whhf, bhhf, Whhb, bhhb, xp4, hbuf, done);
    fc_kernel<<<B_, 192, 0, stream>>>(hbuf, fcW, fcb, out);
}

// Round 19
// 462.921 us; speedup vs baseline: 2.2572x; 2.2572x over previous
//
#include <hip/hip_runtime.h>
#include <hip/hip_bf16.h>
#include <cstddef>
#include <cstdint>

// ---------------------------------------------------------------- types
typedef __bf16 bf16_t;
typedef __fp16 fp16_t;
typedef __attribute__((ext_vector_type(2))) __fp16 h16x2;   // builtin-native f16 pair
typedef __attribute__((ext_vector_type(8))) __bf16 bf16x8;
typedef __attribute__((ext_vector_type(4))) float f32x4;
typedef __attribute__((ext_vector_type(2))) unsigned u32x2;

#define B_  64
#define T_  2048
#define E_  512
#define H_  32
#define G_  96          // 3*H
#define N2_ 192         // both directions
#define OUT_ 131

//  r,z: scaled by C1 = -log2(e)  -> sigmoid(a) = rcp(1+exp2(C1*a))
//  n:   scaled by C2 = 2*log2(e) -> tanh(y)    = 1-2*rcp(1+exp2(C2*y))
#define C1_ (-1.44269504088896340736f)
#define C2_ ( 2.88539008177792681472f)

// ---- DPP row-rotate. Builtin form: compiler knows DPP semantics and inserts
// the required VALU->DPP wait states (the silent corruption in R13/R16 was an
// inline-asm DPP reading a just-written VGPR with no hazard nops).
#if __has_builtin(__builtin_amdgcn_mov_dpp)
#define DPPROT(out_, in_, N_) (out_) = __builtin_amdgcn_mov_dpp((in_), 0x120 + (N_), 0xf, 0xf, false)
#else
#define DPPROT(out_, in_, N_)                                               \
    asm("s_nop 1\n\ts_nop 1\n\tv_mov_b32_dpp %0, %1 row_ror:" #N_           \
        " row_mask:0xf bank_mask:0xf" : "=v"(out_) : "v"(in_))
#endif

// ---------------------------------------------------------------- prep: W_ih->bf16, bias = b_ih (+ b_hh for r,z)
__global__ void prep_kernel(const float* __restrict__ Wf, const float* __restrict__ Wb,
                            const float* __restrict__ bf_, const float* __restrict__ bb_,
                            const float* __restrict__ bhf, const float* __restrict__ bhb,
                            bf16_t* __restrict__ Wbf, float* __restrict__ bias) {
    int idx = blockIdx.x * 256 + threadIdx.x;        // 0 .. 98303
    int g = idx >> 9, k = idx & 511;
    float v = (g < G_) ? Wf[g * E_ + k] : Wb[(g - G_) * E_ + k];
    Wbf[idx] = (bf16_t)v;
    if (idx < N2_) {
        int dn = (idx >= G_) ? 1 : 0;
        int lg = idx - G_ * dn;
        const float* bi = dn ? bb_ : bf_;
        const float* bh = dn ? bhb : bhf;
        bias[idx] = bi[lg] + ((lg < 64) ? bh[lg] : 0.0f);   // fold b_hh for r,z only
    }
}

// ---------------------------------------------------------------- projection GEMM
// PACKED output: xp4[ ((b*512 + t4)*192 + col) * 4 + e ]  (col = dir*96+gate*32+j,
// e = t&3). bwd cols stored TIME-REVERSED about len-1. Grid: x = n-block
// (2, innermost -> both consumers of each x-tile dispatch-adjacent, L2 reuse).
__global__ __launch_bounds__(256) void proj_kernel(
    const float* __restrict__ x,        // [131072][512] f32
    const bf16_t* __restrict__ Wbf,     // [192][512] bf16
    const float* __restrict__ bias,     // [192]
    const int*   __restrict__ srcl,     // [64]
    float* __restrict__ xp4)            // packed, prescaled
{
    __shared__ bf16_t Alds[64][72];
    __shared__ bf16_t Blds[96][72];

    const int tid  = threadIdx.x;
    const int lane = tid & 63;
    const int w    = tid >> 6;
    const int wm   = w & 1;
    const int wn   = w >> 1;
    const int m0   = blockIdx.y * 64;
    const int n0   = blockIdx.x * 96;

    const int arow = tid >> 2;
    const int acol = (tid & 3) * 16;

    f32x4 acc[2][3];
    #pragma unroll
    for (int i = 0; i < 2; ++i)
        #pragma unroll
        for (int jn = 0; jn < 3; ++jn)
            acc[i][jn] = (f32x4){0.f, 0.f, 0.f, 0.f};

    for (int kt = 0; kt < 8; ++kt) {
        const int c0 = kt * 64;
        __syncthreads();
        {
            const float* asrc = x + (size_t)(m0 + arow) * E_ + c0 + acol;
            float4 v0 = *(const float4*)(asrc + 0);
            float4 v1 = *(const float4*)(asrc + 4);
            float4 v2 = *(const float4*)(asrc + 8);
            float4 v3 = *(const float4*)(asrc + 12);
            bf16x8 pa, pb;
            pa[0]=(bf16_t)v0.x; pa[1]=(bf16_t)v0.y; pa[2]=(bf16_t)v0.z; pa[3]=(bf16_t)v0.w;
            pa[4]=(bf16_t)v1.x; pa[5]=(bf16_t)v1.y; pa[6]=(bf16_t)v1.z; pa[7]=(bf16_t)v1.w;
            pb[0]=(bf16_t)v2.x; pb[1]=(bf16_t)v2.y; pb[2]=(bf16_t)v2.z; pb[3]=(bf16_t)v2.w;
            pb[4]=(bf16_t)v3.x; pb[5]=(bf16_t)v3.y; pb[6]=(bf16_t)v3.z; pb[7]=(bf16_t)v3.w;
            *(bf16x8*)&Alds[arow][acol]     = pa;
            *(bf16x8*)&Alds[arow][acol + 8] = pb;
        }
        #pragma unroll
        for (int i = 0; i < 3; ++i) {
            int u = tid + i * 256;
            int brow = u >> 3, koff = (u & 7) * 8;
            bf16x8 bv = *(const bf16x8*)(Wbf + (size_t)(n0 + brow) * E_ + c0 + koff);
            *(bf16x8*)&Blds[brow][koff] = bv;
        }
        __syncthreads();
        #pragma unroll
        for (int ks = 0; ks < 2; ++ks) {
            bf16x8 af[2], bfr[3];
            #pragma unroll
            for (int i = 0; i < 2; ++i)
                af[i] = *(const bf16x8*)&Alds[wm * 32 + i * 16 + (lane & 15)][ks * 32 + (lane >> 4) * 8];
            #pragma unroll
            for (int jn = 0; jn < 3; ++jn)
                bfr[jn] = *(const bf16x8*)&Blds[wn * 48 + jn * 16 + (lane & 15)][ks * 32 + (lane >> 4) * 8];
            #pragma unroll
            for (int i = 0; i < 2; ++i)
                #pragma unroll
                for (int jn = 0; jn < 3; ++jn)
                    acc[i][jn] = __builtin_amdgcn_mfma_f32_16x16x32_bf16(af[i], bfr[jn], acc[i][jn], 0, 0, 0);
        }
    }
    // ---- epilogue
    const int bb = m0 >> 11;                 // uniform batch index
    int len = srcl[bb];
    if (len < 1) len = 1;
    if (len > T_) len = T_;
    float* xb4 = xp4 + (size_t)bb * 512 * N2_ * 4;
    #pragma unroll
    for (int i = 0; i < 2; ++i)
        #pragma unroll
        for (int jn = 0; jn < 3; ++jn) {
            int mg = m0 + wm * 32 + i * 16 + ((lane >> 4) & 3) * 4;   // t, t+1.. (aligned 4)
            int ng = n0 + wn * 48 + jn * 16 + (lane & 15);
            int lg = (ng >= G_) ? ng - G_ : ng;
            float scl = (lg < 64) ? C1_ : C2_;
            float bv  = bias[ng];
            int t = mg & (T_ - 1);
            if (ng < G_) {                       // fwd: float4 along t
                f32x4 v;
                #pragma unroll
                for (int r = 0; r < 4; ++r) v[r] = scl * (acc[i][jn][r] + bv);
                *(f32x4*)(xb4 + ((size_t)(t >> 2) * N2_ + ng) * 4) = v;
            } else {                             // bwd: reversed scalar stores
                #pragma unroll
                for (int r = 0; r < 4; ++r) {
                    int trow = len - 1 - (t + r);
                    if (trow < 0) trow += T_;
                    xb4[((size_t)(trow >> 2) * N2_ + ng) * 4 + (trow & 3)] =
                        scl * (acc[i][jn][r] + bv);
                }
            }
        }
}

// ---------------------------------------------------------------- GRU recurrence (split-k f16 dot2 step)
// One block per (batch, dir) -> 128 blocks. Lane l: m=l&15, r16=(l>>4)&1,
// p32=l>>5, j=l&31. Lanes l and l^32 share output j; p32 splits the 16
// (k,k^16) dot2-pairs into two 8-groups (rotations i+8*p32) -> 24 fdot2 +
// sum-invariant permlane32 reduce. All DPP via hazard-safe builtin.
__global__ __launch_bounds__(64) void gru_rec_kernel(
    const float* __restrict__ xp4,      // packed, prescaled, bwd-reversed
    const int*   __restrict__ src_len,  // [B]
    const float* __restrict__ Whh_f, const float* __restrict__ bhh_f,
    const float* __restrict__ Whh_b, const float* __restrict__ bhh_b,
    float* __restrict__ hout)           // [B][64]
{
    const int blk  = blockIdx.x;
    const int b    = blk >> 1;
    const int dir  = blk & 1;
    const int l    = threadIdx.x;
    const int m    = l & 15;
    const int r16  = (l >> 4) & 1;
    const int p32  = l >> 5;            // rotation group
    const int j    = l & 31;

    const float* Whh = dir ? Whh_b : Whh_f;
    const float* bhh = dir ? bhh_b : bhh_f;

    // probe DPP row_ror:1 direction: rotation i delivers lane (m + s*i)&15's value
    int s_dir;
    {
        int q1;
        DPPROT(q1, m, 1);
        s_dir = (__builtin_amdgcn_readfirstlane(q1) == 1) ? 1 : -1;
    }

    // pre-permuted prescaled f16 weight pairs: at group step i, this lane's data
    // pair is (h[c+16*r16], h[c+16*(1-r16)]) with c=(m+s*(i+8*p32))&15.
    h16x2 wr[8], wz[8], wn[8];
    #pragma unroll
    for (int i = 0; i < 8; ++i) {
        int c  = (m + s_dir * (i + 8 * p32)) & 15;
        int ka = c + 16 * r16;
        int kb = c + 16 * (1 - r16);
        wr[i] = (h16x2){(fp16_t)(C1_ * Whh[(j)      * H_ + ka]), (fp16_t)(C1_ * Whh[(j)      * H_ + kb])};
        wz[i] = (h16x2){(fp16_t)(C1_ * Whh[(32 + j) * H_ + ka]), (fp16_t)(C1_ * Whh[(32 + j) * H_ + kb])};
        wn[i] = (h16x2){(fp16_t)(C2_ * Whh[(64 + j) * H_ + ka]), (fp16_t)(C2_ * Whh[(64 + j) * H_ + kb])};
    }
    const float bnseed = p32 ? 0.0f : (C2_ * bhh[64 + j]);   // n-gate b_hh once

#if __has_builtin(__builtin_amdgcn_permlane16_swap)
    bool useX;      // R12-proven marshal probe (partner over l^16)
    {
        u32x2 pr = __builtin_amdgcn_permlane16_swap((unsigned)l, (unsigned)l, false, false);
        useX = (pr.x == (unsigned)(l ^ 16));
    }
#endif

    int len = src_len[b];
    if (len < 1) len = 1;
    if (len > T_) len = T_;
    len = __builtin_amdgcn_readfirstlane(len);

    const int off = dir * G_ + j;                // per-lane column (same for both p32)
    const float* xb4 = xp4 + (size_t)b * 512 * N2_ * 4;

    float hval = 0.0f;

    auto LB = [&](int q4, f32x4& vr, f32x4& vz, f32x4& vn) {
        int qq = (q4 < 512) ? q4 : 511;          // uniform clamp; clamped blocks never consumed
        const f32x4* pp = (const f32x4*)(xb4 + ((size_t)qq * N2_ + off) * 4);
        vr = pp[0]; vz = pp[32]; vn = pp[64];
    };

    auto pl32sum = [&](float a) -> float {       // a + a[l^32], convention-proof (sum of both outs)
#if __has_builtin(__builtin_amdgcn_permlane32_swap)
        u32x2 rr = __builtin_amdgcn_permlane32_swap(__float_as_uint(a), __float_as_uint(a), false, false);
        return __uint_as_float(rr.x) + __uint_as_float(rr.y);
#else
        return a + __int_as_float(__builtin_amdgcn_ds_bpermute((l ^ 32) << 2, __float_as_int(a)));
#endif
    };

    auto step = [&](float xr, float xz, float xn) {
        // marshal (R12-proven): f16 pair (h[j], h[j^16]) via l^16 partner
        float hB;
#if __has_builtin(__builtin_amdgcn_permlane16_swap)
        {
            u32x2 sw = __builtin_amdgcn_permlane16_swap(
                __float_as_uint(hval), __float_as_uint(hval), false, false);
            hB = __uint_as_float(useX ? sw.x : sw.y);
        }
#else
        hB = __int_as_float(__builtin_amdgcn_ds_bpermute((l ^ 16) << 2, __float_as_int(hval)));
#endif
        auto q0 = __builtin_amdgcn_cvt_pkrtz(hval, hB);   // __fp16 x2
        int qb = __builtin_bit_cast(int, q0);
        int qb8;
        DPPROT(qb8, qb, 8);                      // hazard-safe (builtin / padded asm)
        int qc = p32 ? qb8 : qb;                 // group base rotation: 8*p32
        // 8 dot2-pairs per gate, direct rotations from qc
        float ar = 0.f, az = 0.f, an = bnseed;
        {
            h16x2 p_ = __builtin_bit_cast(h16x2, qc);
            ar = __builtin_amdgcn_fdot2(p_, wr[0], ar, false);
            az = __builtin_amdgcn_fdot2(p_, wz[0], az, false);
            an = __builtin_amdgcn_fdot2(p_, wn[0], an, false);
        }
#define DOTI(N_)                                                    \
        {   int rb_;                                                \
            DPPROT(rb_, qc, N_);                                    \
            h16x2 p_ = __builtin_bit_cast(h16x2, rb_);              \
            ar = __builtin_amdgcn_fdot2(p_, wr[N_], ar, false);     \
            az = __builtin_amdgcn_fdot2(p_, wz[N_], az, false);     \
            an = __builtin_amdgcn_fdot2(p_, wn[N_], an, false);     }
        DOTI(1) DOTI(2) DOTI(3) DOTI(4) DOTI(5) DOTI(6) DOTI(7)
#undef DOTI
        // reduce over p32 (l^32, sum-invariant) + x seeds
        float arf = pl32sum(ar) + xr;
        float azf = pl32sum(az) + xz;
        float anf = pl32sum(an);
        // gates
        float er = __builtin_amdgcn_exp2f(arf);
        float rg = __builtin_amdgcn_rcpf(1.0f + er);     // sigmoid r
        float ez = __builtin_amdgcn_exp2f(azf);
        float zg = __builtin_amdgcn_rcpf(1.0f + ez);     // sigmoid z
        float na = __builtin_fmaf(rg, anf, xn);          // C2*(xn + r*(hn+bhn))
        float eu = __builtin_amdgcn_exp2f(na);
        float u  = __builtin_amdgcn_rcpf(1.0f + eu);     // n = 1-2u
        float m2 = -(ez + ez);
        float hp = hval + ez;
        hval = zg * __builtin_fmaf(m2, u, hp);           // h' = z*(h+ez-2ez*u)
    };

    // ---- pipeline: two 4-step float4 blocks in flight
    f32x4 Ar, Az, An, Cr, Cz, Cn;
    LB(0, Ar, Az, An);
    LB(1, Cr, Cz, Cn);
    int s = 0;
    while (s + 8 <= len) {
        step(Ar[0], Az[0], An[0]);
        step(Ar[1], Az[1], An[1]);
        step(Ar[2], Az[2], An[2]);
        step(Ar[3], Az[3], An[3]);
        LB((s >> 2) + 2, Ar, Az, An);
        step(Cr[0], Cz[0], Cn[0]);
        step(Cr[1], Cz[1], Cn[1]);
        step(Cr[2], Cz[2], Cn[2]);
        step(Cr[3], Cz[3], Cn[3]);
        LB((s >> 2) + 3, Cr, Cz, Cn);
        s += 8;
    }
    #pragma unroll
    for (int d = 0; d < 4; ++d)
        if (s + d < len) step(Ar[d], Az[d], An[d]);
    #pragma unroll
    for (int d = 0; d < 4; ++d)
        if (s + 4 + d < len) step(Cr[d], Cz[d], Cn[d]);

    if (p32 == 0) hout[b * 64 + dir * 32 + j] = hval;
}

// ---------------------------------------------------------------- final fc
__global__ __launch_bounds__(192) void fc_kernel(
    const float* __restrict__ hbuf,     // [64][64]
    const float* __restrict__ fcW,      // [131][64]
    const float* __restrict__ fcb,      // [131]
    float* __restrict__ out)            // [64][131]
{
    __shared__ float hrow[64];
    const int b = blockIdx.x, tid = threadIdx.x;
    if (tid < 64) hrow[tid] = hbuf[b * 64 + tid];
    __syncthreads();
    if (tid < OUT_) {
        float acc = fcb[tid];
        #pragma unroll
        for (int i = 0; i < 64; ++i)
            acc = __builtin_fmaf(hrow[i], fcW[tid * 64 + i], acc);
        out[b * OUT_ + tid] = acc;
    }
}

// ---------------------------------------------------------------- launch
extern "C" void kernel_launch(void* const* d_in, const int* in_sizes, int n_in,
                              void* d_out, int out_size, void* d_ws, size_t ws_size,
                              hipStream_t stream) {
    const float* x    = (const float*)d_in[0];
    const int*   srcl = (const int*)  d_in[1];
    const float* Wihf = (const float*)d_in[3];
    const float* Whhf = (const float*)d_in[4];
    const float* bihf = (const float*)d_in[5];
    const float* bhhf = (const float*)d_in[6];
    const float* Wihb = (const float*)d_in[7];
    const float* Whhb = (const float*)d_in[8];
    const float* bihb = (const float*)d_in[9];
    const float* bhhb = (const float*)d_in[10];
    const float* fcW  = (const float*)d_in[11];
    const float* fcb  = (const float*)d_in[12];
    float* out = (float*)d_out;

    const size_t XP_BYTES   = (size_t)B_ * T_ * N2_ * 4;   // 100,663,296
    const size_t HBUF_BYTES = (size_t)B_ * 64 * 4;
    const size_t BIAS_BYTES = 1024;
    const size_t WBF_BYTES  = (size_t)N2_ * E_ * 2;
    if (ws_size < XP_BYTES + HBUF_BYTES + BIAS_BYTES + WBF_BYTES) return;

    char* ws = (char*)d_ws;
    float*  xp4  = (float*)ws;
    float*  hbuf = (float*)(ws + XP_BYTES);
    float*  bias = (float*)(ws + XP_BYTES + HBUF_BYTES);
    bf16_t* Wbf  = (bf16_t*)(ws + XP_BYTES + HBUF_BYTES + BIAS_BYTES);

    prep_kernel<<<384, 256, 0, stream>>>(Wihf, Wihb, bihf, bihb, bhhf, bhhb, Wbf, bias);
    dim3 pg(2, (B_ * T_) / 64);            // n innermost -> x-tile reuse in L2/L3
    proj_kernel<<<pg, 256, 0, stream>>>(x, Wbf, bias, srcl, xp4);
    gru_rec_kernel<<<B_ * 2, 64, 0, stream>>>(xp4, srcl, Whhf, bhhf, Whhb, bhhb, hbuf);
    fc_kernel<<<B_, 192, 0, stream>>>(hbuf, fcW, fcb, out);
}

// Round 20
// 454.835 us; speedup vs baseline: 2.2973x; 1.0178x over previous
//
#include <hip/hip_runtime.h>
#include <hip/hip_bf16.h>
#include <cstddef>
#include <cstdint>

// ---------------------------------------------------------------- types
typedef __bf16 bf16_t;
typedef __fp16 fp16_t;
typedef __attribute__((ext_vector_type(2))) __fp16 h16x2;   // builtin-native f16 pair
typedef __attribute__((ext_vector_type(8))) __bf16 bf16x8;
typedef __attribute__((ext_vector_type(4))) float f32x4;
typedef __attribute__((ext_vector_type(2))) unsigned u32x2;

#define B_  64
#define T_  2048
#define E_  512
#define H_  32
#define G_  96          // 3*H
#define N2_ 192         // both directions
#define OUT_ 131

//  r,z: scaled by C1 = -log2(e)  -> sigmoid(a) = rcp(1+exp2(C1*a))
//  n:   scaled by C2 = 2*log2(e) -> tanh(y)    = 1-2*rcp(1+exp2(C2*y))
#define C1_ (-1.44269504088896340736f)
#define C2_ ( 2.88539008177792681472f)

// single-instruction DPP rotate within 16-lane rows (no tied old-copy).
// NOTE: safe here ONLY because every use reads a register written >=3 VALU
// instructions earlier (the i=0 fdot2 group intervenes). DPP reading a
// just-written VGPR from inline asm silently corrupts (R13/R16 lesson).
#define MOVDPP(out_, in_, N_)                                               \
    asm("v_mov_b32_dpp %0, %1 row_ror:" #N_ " row_mask:0xf bank_mask:0xf"   \
        : "=v"(out_) : "v"(in_))

// ---------------------------------------------------------------- prep: W_ih->bf16, bias = b_ih (+ b_hh for r,z)
__global__ void prep_kernel(const float* __restrict__ Wf, const float* __restrict__ Wb,
                            const float* __restrict__ bf_, const float* __restrict__ bb_,
                            const float* __restrict__ bhf, const float* __restrict__ bhb,
                            bf16_t* __restrict__ Wbf, float* __restrict__ bias) {
    int idx = blockIdx.x * 256 + threadIdx.x;        // 0 .. 98303
    int g = idx >> 9, k = idx & 511;
    float v = (g < G_) ? Wf[g * E_ + k] : Wb[(g - G_) * E_ + k];
    Wbf[idx] = (bf16_t)v;
    if (idx < N2_) {
        int dn = (idx >= G_) ? 1 : 0;
        int lg = idx - G_ * dn;
        const float* bi = dn ? bb_ : bf_;
        const float* bh = dn ? bhb : bhf;
        bias[idx] = bi[lg] + ((lg < 64) ? bh[lg] : 0.0f);   // fold b_hh for r,z only
    }
}

// ---------------------------------------------------------------- projection GEMM
// PACKED output: xp4[ ((b*512 + t4)*192 + col) * 4 + e ]  (col = dir*96+gate*32+j,
// e = t&3). bwd cols stored TIME-REVERSED about len-1. Grid: x = n-block
// (2, innermost -> both consumers of each x-tile dispatch-adjacent, L2 reuse).
__global__ __launch_bounds__(256) void proj_kernel(
    const float* __restrict__ x,        // [131072][512] f32
    const bf16_t* __restrict__ Wbf,     // [192][512] bf16
    const float* __restrict__ bias,     // [192]
    const int*   __restrict__ srcl,     // [64]
    float* __restrict__ xp4)            // packed, prescaled
{
    __shared__ bf16_t Alds[64][72];
    __shared__ bf16_t Blds[96][72];

    const int tid  = threadIdx.x;
    const int lane = tid & 63;
    const int w    = tid >> 6;
    const int wm   = w & 1;
    const int wn   = w >> 1;
    const int m0   = blockIdx.y * 64;
    const int n0   = blockIdx.x * 96;

    const int arow = tid >> 2;
    const int acol = (tid & 3) * 16;

    f32x4 acc[2][3];
    #pragma unroll
    for (int i = 0; i < 2; ++i)
        #pragma unroll
        for (int jn = 0; jn < 3; ++jn)
            acc[i][jn] = (f32x4){0.f, 0.f, 0.f, 0.f};

    for (int kt = 0; kt < 8; ++kt) {
        const int c0 = kt * 64;
        __syncthreads();
        {
            const float* asrc = x + (size_t)(m0 + arow) * E_ + c0 + acol;
            float4 v0 = *(const float4*)(asrc + 0);
            float4 v1 = *(const float4*)(asrc + 4);
            float4 v2 = *(const float4*)(asrc + 8);
            float4 v3 = *(const float4*)(asrc + 12);
            bf16x8 pa, pb;
            pa[0]=(bf16_t)v0.x; pa[1]=(bf16_t)v0.y; pa[2]=(bf16_t)v0.z; pa[3]=(bf16_t)v0.w;
            pa[4]=(bf16_t)v1.x; pa[5]=(bf16_t)v1.y; pa[6]=(bf16_t)v1.z; pa[7]=(bf16_t)v1.w;
            pb[0]=(bf16_t)v2.x; pb[1]=(bf16_t)v2.y; pb[2]=(bf16_t)v2.z; pb[3]=(bf16_t)v2.w;
            pb[4]=(bf16_t)v3.x; pb[5]=(bf16_t)v3.y; pb[6]=(bf16_t)v3.z; pb[7]=(bf16_t)v3.w;
            *(bf16x8*)&Alds[arow][acol]     = pa;
            *(bf16x8*)&Alds[arow][acol + 8] = pb;
        }
        #pragma unroll
        for (int i = 0; i < 3; ++i) {
            int u = tid + i * 256;
            int brow = u >> 3, koff = (u & 7) * 8;
            bf16x8 bv = *(const bf16x8*)(Wbf + (size_t)(n0 + brow) * E_ + c0 + koff);
            *(bf16x8*)&Blds[brow][koff] = bv;
        }
        __syncthreads();
        #pragma unroll
        for (int ks = 0; ks < 2; ++ks) {
            bf16x8 af[2], bfr[3];
            #pragma unroll
            for (int i = 0; i < 2; ++i)
                af[i] = *(const bf16x8*)&Alds[wm * 32 + i * 16 + (lane & 15)][ks * 32 + (lane >> 4) * 8];
            #pragma unroll
            for (int jn = 0; jn < 3; ++jn)
                bfr[jn] = *(const bf16x8*)&Blds[wn * 48 + jn * 16 + (lane & 15)][ks * 32 + (lane >> 4) * 8];
            #pragma unroll
            for (int i = 0; i < 2; ++i)
                #pragma unroll
                for (int jn = 0; jn < 3; ++jn)
                    acc[i][jn] = __builtin_amdgcn_mfma_f32_16x16x32_bf16(af[i], bfr[jn], acc[i][jn], 0, 0, 0);
        }
    }
    // ---- epilogue: rows are 4 consecutive t -> float4 along t for fwd
    const int bb = m0 >> 11;                 // uniform batch index
    int len = srcl[bb];
    if (len < 1) len = 1;
    if (len > T_) len = T_;
    float* xb4 = xp4 + (size_t)bb * 512 * N2_ * 4;
    #pragma unroll
    for (int i = 0; i < 2; ++i)
        #pragma unroll
        for (int jn = 0; jn < 3; ++jn) {
            int mg = m0 + wm * 32 + i * 16 + ((lane >> 4) & 3) * 4;   // t, t+1.. (aligned 4)
            int ng = n0 + wn * 48 + jn * 16 + (lane & 15);
            int lg = (ng >= G_) ? ng - G_ : ng;
            float scl = (lg < 64) ? C1_ : C2_;
            float bv  = bias[ng];
            int t = mg & (T_ - 1);
            if (ng < G_) {                       // fwd: float4 along t
                f32x4 v;
                #pragma unroll
                for (int r = 0; r < 4; ++r) v[r] = scl * (acc[i][jn][r] + bv);
                *(f32x4*)(xb4 + ((size_t)(t >> 2) * N2_ + ng) * 4) = v;
            } else {                             // bwd: reversed scalar stores
                #pragma unroll
                for (int r = 0; r < 4; ++r) {
                    int trow = len - 1 - (t + r);
                    if (trow < 0) trow += T_;
                    xb4[((size_t)(trow >> 2) * N2_ + ng) * 4 + (trow & 3)] =
                        scl * (acc[i][jn][r] + bv);
                }
            }
        }
}

// ---------------------------------------------------------------- GRU recurrence (f16 dot2 step)
// One block per batch; lane l: dir=l>>5, j=l&31 (m=l&15, row=(l>>4)&1). Per step:
//   hB = permlane16_swap(h); q = cvt_pkrtz(h, hB)  (f16 pair (h[j], h[j^16]))
//   15x DPP row_ror rotate q; 48x v_dot2_f32_f16 with pre-permuted f16 weight
//   pairs; scalar f32 accumulators seeded with xr/xz/bn -> no inits, no reduce.
__global__ __launch_bounds__(64) void gru_rec_kernel(
    const float* __restrict__ xp4,      // packed, prescaled, bwd-reversed
    const int*   __restrict__ src_len,  // [B]
    const float* __restrict__ Whh_f, const float* __restrict__ bhh_f,
    const float* __restrict__ Whh_b, const float* __restrict__ bhh_b,
    float* __restrict__ hout)           // [B][64]
{
    const int b    = blockIdx.x;
    const int l    = threadIdx.x;
    const int m    = l & 15;
    const int r16  = (l >> 4) & 1;
    const int dir  = l >> 5;
    const int j    = l & 31;

    const float* Whh = dir ? Whh_b : Whh_f;
    const float* bhh = dir ? bhh_b : bhh_f;

    // probe DPP row_ror:1 direction: rotation i delivers lane (m + s*i)&15's value
    int s_dir;
    {
        int q1;
        MOVDPP(q1, m, 1);
        s_dir = (__builtin_amdgcn_readfirstlane(q1) == 1) ? 1 : -1;
    }

    // pre-permuted prescaled f16 weight pairs: at rotation i, lane holds pair
    // (h[c+16*r16], h[c+16*(1-r16)]) with c=(m+s*i)&15 -> matching W columns.
    h16x2 wr[16], wz[16], wn[16];
    #pragma unroll
    for (int i = 0; i < 16; ++i) {
        int c  = (m + s_dir * i) & 15;
        int ka = c + 16 * r16;
        int kb = c + 16 * (1 - r16);
        wr[i] = (h16x2){(fp16_t)(C1_ * Whh[(j)      * H_ + ka]), (fp16_t)(C1_ * Whh[(j)      * H_ + kb])};
        wz[i] = (h16x2){(fp16_t)(C1_ * Whh[(32 + j) * H_ + ka]), (fp16_t)(C1_ * Whh[(32 + j) * H_ + kb])};
        wn[i] = (h16x2){(fp16_t)(C2_ * Whh[(64 + j) * H_ + ka]), (fp16_t)(C2_ * Whh[(64 + j) * H_ + kb])};
    }
    const float bn = C2_ * bhh[64 + j];          // n-gate b_hh (inside r-multiply)

#if __has_builtin(__builtin_amdgcn_permlane16_swap)
    bool useX;
    {
        u32x2 pr = __builtin_amdgcn_permlane16_swap((unsigned)l, (unsigned)l, false, false);
        useX = (pr.x == (unsigned)(l ^ 16));
    }
#endif

    int len = src_len[b];
    if (len < 1) len = 1;
    if (len > T_) len = T_;
    len = __builtin_amdgcn_readfirstlane(len);

    const int off = dir * G_ + j;                // per-lane column
    const float* xb4 = xp4 + (size_t)b * 512 * N2_ * 4;

    float hval = 0.0f;

    auto LB = [&](int q4, f32x4& vr, f32x4& vz, f32x4& vn) {
        int qq = (q4 < 512) ? q4 : 511;          // uniform clamp; always-written region
        const f32x4* p = (const f32x4*)(xb4 + ((size_t)qq * N2_ + off) * 4);
        vr = p[0]; vz = p[32]; vn = p[64];
    };

    auto step = [&](float xr, float xz, float xn) {
        // marshal: f16 pair (h[j], h[j^16])
        float hB;
#if __has_builtin(__builtin_amdgcn_permlane16_swap)
        {
            u32x2 sw = __builtin_amdgcn_permlane16_swap(
                __float_as_uint(hval), __float_as_uint(hval), false, false);
            hB = __uint_as_float(useX ? sw.x : sw.y);
        }
#else
        hB = __int_as_float(__builtin_amdgcn_ds_bpermute((l ^ 16) << 2, __float_as_int(hval)));
#endif
        auto q0 = __builtin_amdgcn_cvt_pkrtz(hval, hB);   // __fp16 x2
        int qb = __builtin_bit_cast(int, q0);
        // accumulate: acc = dot2(P_i, w[i], acc); seeds = xr/xz/bn (no init instrs)
        float ar = xr, az = xz, an = bn;
        {
            h16x2 p0 = __builtin_bit_cast(h16x2, qb);
            ar = __builtin_amdgcn_fdot2(p0, wr[0], ar, false);
            az = __builtin_amdgcn_fdot2(p0, wz[0], az, false);
            an = __builtin_amdgcn_fdot2(p0, wn[0], an, false);
        }
#define DOTI(N_)                                                    \
        {   int rb_;                                                \
            MOVDPP(rb_, qb, N_);                                    \
            h16x2 p_ = __builtin_bit_cast(h16x2, rb_);              \
            ar = __builtin_amdgcn_fdot2(p_, wr[N_], ar, false);     \
            az = __builtin_amdgcn_fdot2(p_, wz[N_], az, false);     \
            an = __builtin_amdgcn_fdot2(p_, wn[N_], an, false);     }
        DOTI(1)  DOTI(2)  DOTI(3)  DOTI(4)  DOTI(5)
        DOTI(6)  DOTI(7)  DOTI(8)  DOTI(9)  DOTI(10)
        DOTI(11) DOTI(12) DOTI(13) DOTI(14) DOTI(15)
#undef DOTI
        // gates
        float er = __builtin_amdgcn_exp2f(ar);
        float rg = __builtin_amdgcn_rcpf(1.0f + er);     // sigmoid r
        float ez = __builtin_amdgcn_exp2f(az);
        float zg = __builtin_amdgcn_rcpf(1.0f + ez);     // sigmoid z
        float na = __builtin_fmaf(rg, an, xn);           // C2*(xn + r*(hn+bhn))
        float eu = __builtin_amdgcn_exp2f(na);
        float u  = __builtin_amdgcn_rcpf(1.0f + eu);     // n = 1-2u
        float m2 = -(ez + ez);
        float hp = hval + ez;
        hval = zg * __builtin_fmaf(m2, u, hp);           // h' = z*(h+ez-2ez*u)
    };

    // ---- pipeline: two 4-step float4 blocks in flight
    f32x4 Ar, Az, An, Cr, Cz, Cn;
    LB(0, Ar, Az, An);
    LB(1, Cr, Cz, Cn);
    int s = 0;
    while (s + 8 <= len) {
        step(Ar[0], Az[0], An[0]);
        step(Ar[1], Az[1], An[1]);
        step(Ar[2], Az[2], An[2]);
        step(Ar[3], Az[3], An[3]);
        LB((s >> 2) + 2, Ar, Az, An);
        step(Cr[0], Cz[0], Cn[0]);
        step(Cr[1], Cz[1], Cn[1]);
        step(Cr[2], Cz[2], Cn[2]);
        step(Cr[3], Cz[3], Cn[3]);
        LB((s >> 2) + 3, Cr, Cz, Cn);
        s += 8;
    }
    #pragma unroll
    for (int d = 0; d < 4; ++d)
        if (s + d < len) step(Ar[d], Az[d], An[d]);
    #pragma unroll
    for (int d = 0; d < 4; ++d)
        if (s + 4 + d < len) step(Cr[d], Cz[d], Cn[d]);

    hout[b * 64 + dir * 32 + j] = hval;
}

// ---------------------------------------------------------------- final fc
__global__ __launch_bounds__(192) void fc_kernel(
    const float* __restrict__ hbuf,     // [64][64]
    const float* __restrict__ fcW,      // [131][64]
    const float* __restrict__ fcb,      // [131]
    float* __restrict__ out)            // [64][131]
{
    __shared__ float hrow[64];
    const int b = blockIdx.x, tid = threadIdx.x;
    if (tid < 64) hrow[tid] = hbuf[b * 64 + tid];
    __syncthreads();
    if (tid < OUT_) {
        float acc = fcb[tid];
        #pragma unroll
        for (int i = 0; i < 64; ++i)
            acc = __builtin_fmaf(hrow[i], fcW[tid * 64 + i], acc);
        out[b * OUT_ + tid] = acc;
    }
}

// ---------------------------------------------------------------- launch
extern "C" void kernel_launch(void* const* d_in, const int* in_sizes, int n_in,
                              void* d_out, int out_size, void* d_ws, size_t ws_size,
                              hipStream_t stream) {
    const float* x    = (const float*)d_in[0];
    const int*   srcl = (const int*)  d_in[1];
    const float* Wihf = (const float*)d_in[3];
    const float* Whhf = (const float*)d_in[4];
    const float* bihf = (const float*)d_in[5];
    const float* bhhf = (const float*)d_in[6];
    const float* Wihb = (const float*)d_in[7];
    const float* Whhb = (const float*)d_in[8];
    const float* bihb = (const float*)d_in[9];
    const float* bhhb = (const float*)d_in[10];
    const float* fcW  = (const float*)d_in[11];
    const float* fcb  = (const float*)d_in[12];
    float* out = (float*)d_out;

    const size_t XP_BYTES   = (size_t)B_ * T_ * N2_ * 4;   // 100,663,296
    const size_t HBUF_BYTES = (size_t)B_ * 64 * 4;
    const size_t BIAS_BYTES = 1024;
    const size_t WBF_BYTES  = (size_t)N2_ * E_ * 2;
    if (ws_size < XP_BYTES + HBUF_BYTES + BIAS_BYTES + WBF_BYTES) return;

    char* ws = (char*)d_ws;
    float*  xp4  = (float*)ws;
    float*  hbuf = (float*)(ws + XP_BYTES);
    float*  bias = (float*)(ws + XP_BYTES + HBUF_BYTES);
    bf16_t* Wbf  = (bf16_t*)(ws + XP_BYTES + HBUF_BYTES + BIAS_BYTES);

    prep_kernel<<<384, 256, 0, stream>>>(Wihf, Wihb, bihf, bihb, bhhf, bhhb, Wbf, bias);
    dim3 pg(2, (B_ * T_) / 64);            // n innermost -> x-tile reuse in L2/L3
    proj_kernel<<<pg, 256, 0, stream>>>(x, Wbf, bias, srcl, xp4);
    gru_rec_kernel<<<B_, 64, 0, stream>>>(xp4, srcl, Whhf, bhhf, Whhb, bhhb, hbuf);
    fc_kernel<<<B_, 192, 0, stream>>>(hbuf, fcW, fcb, out);
}